// Round 1
// baseline (434.076 us; speedup 1.0000x reference)
//
#include <hip/hip_runtime.h>

// Problem constants (setup_inputs is fixed):
//   x:         (B=16, L=512, D=768) fp32
//   width_emb: (W=8, WD=64) fp32
//   batch_max_seq_len = 512  -> max_width = min(512, 8) = 8
//   n_spans = sum_{w=1..8} (512 - w + 1) = 4068
//   out: (B, 4068, 2*768 + 64 = 1600) fp32  = 416.56 MB
typedef float f32x4 __attribute__((ext_vector_type(4)));

constexpr uint32_t B  = 16;
constexpr uint32_t L  = 512;
constexpr uint32_t D4 = 768 / 4;   // 192 float4 per x row
constexpr uint32_t WD4 = 64 / 4;   // 16 float4 per width_emb row
constexpr uint32_t NSPANS = 4068;
constexpr uint32_t ROW_F4 = 2 * D4 + WD4;                 // 400 float4 per out row
constexpr uint32_t TOTAL_F4 = B * NSPANS * ROW_F4;        // 26,035,200

constexpr uint32_t TPB = 256;
constexpr uint32_t F4_PER_THREAD = 8;                     // 128 B per thread
constexpr uint32_t CHUNK = TPB * F4_PER_THREAD;           // 2048 f4 per block

__global__ __launch_bounds__(TPB) void span_rep_kernel(
    const f32x4* __restrict__ x4,
    const f32x4* __restrict__ w4,
    f32x4* __restrict__ out4) {
  uint32_t idx = blockIdx.x * CHUNK + threadIdx.x;
  if (idx >= TOTAL_F4) return;

  // One division pair per THREAD (not per element); the loop below
  // maintains (r, c) incrementally. 256 < 400 so each +TPB step crosses
  // at most one row boundary.
  uint32_t r = idx / ROW_F4;
  uint32_t c = idx - r * ROW_F4;
  uint32_t b = r / NSPANS;
  uint32_t s = r - b * NSPANS;

  // Width bucket for current s: offset(k) = L*k - k(k-1)/2 is the first
  // span index of bucket k (7 predicated compares, compile-time consts).
  uint32_t wid = 0;
#pragma unroll
  for (uint32_t k = 1; k < 8; ++k) {
    const uint32_t o = L * k - (k * (k - 1)) / 2;
    wid += (s >= o) ? 1u : 0u;
  }
  uint32_t off   = L * wid - (wid * (wid - 1u)) / 2u;
  uint32_t start = s - off;

#pragma unroll
  for (uint32_t i = 0; i < F4_PER_THREAD; ++i) {
    if (idx < TOTAL_F4) {
      f32x4 v;
      if (c < D4) {
        // h_start segment
        v = x4[(b * L + start) * D4 + c];
      } else if (c < 2 * D4) {
        // h_end segment (end = start + wid)
        v = x4[(b * L + start + wid) * D4 + (c - D4)];
      } else {
        // width embedding segment
        v = w4[wid * WD4 + (c - 2 * D4)];
      }
      // out is write-once streaming: non-temporal keeps L2 for x reads.
      __builtin_nontemporal_store(v, &out4[idx]);
    }
    // Advance this thread to idx + TPB with incremental bookkeeping.
    idx += TPB;
    c   += TPB;
    if (c >= ROW_F4) {
      c -= ROW_F4;
      ++start;
      ++s;
      if (s == NSPANS) {            // next batch
        ++b; s = 0; wid = 0; start = 0;
      } else if (start == L - wid) { // next width bucket (bucket wid has L-wid spans)
        ++wid; start = 0;
      }
    }
  }
}

extern "C" void kernel_launch(void* const* d_in, const int* in_sizes, int n_in,
                              void* d_out, int out_size, void* d_ws, size_t ws_size,
                              hipStream_t stream) {
  const f32x4* x4 = (const f32x4*)d_in[0];
  const f32x4* w4 = (const f32x4*)d_in[1];
  f32x4* out4 = (f32x4*)d_out;

  uint32_t blocks = (TOTAL_F4 + CHUNK - 1u) / CHUNK;  // 12,713
  span_rep_kernel<<<dim3(blocks), dim3(TPB), 0, stream>>>(x4, w4, out4);
}